// Round 10
// baseline (165.988 us; speedup 1.0000x reference)
//
#include <hip/hip_runtime.h>

#define T_SEQ 4096
#define NBATCH 4
#define EMB 1024
#define HS 64
#define BT (NBATCH * T_SEQ)   // 16384 token rows

typedef float f32x4 __attribute__((ext_vector_type(4)));
typedef short s16x8 __attribute__((ext_vector_type(8)));

__device__ __forceinline__ unsigned short f2bf(float x) {  // RNE fp32->bf16
  union { float f; unsigned u; } c; c.f = x;
  unsigned r = c.u + 0x7FFF + ((c.u >> 16) & 1);
  return (unsigned short)(r >> 16);
}
__device__ __forceinline__ float bf2f(unsigned short h) {
  union { unsigned u; float f; } c; c.u = ((unsigned)h) << 16;
  return c.f;
}
// packed RNE fp32x2 -> bf16x2 (single HW instr; S0->lo, S1->hi — T12 recipe)
__device__ __forceinline__ unsigned cvtpk(float lo, float hi) {
  unsigned r;
  asm("v_cvt_pk_bf16_f32 %0, %1, %2" : "=v"(r) : "v"(lo), "v"(hi));
  return r;
}
// RNE hi/lo split (cold paths: wconv, epilogues, attn Q)
__device__ __forceinline__ void cvt8(float4 a0, float4 a1, s16x8& hi, s16x8& lo) {
  float xv[8] = {a0.x, a0.y, a0.z, a0.w, a1.x, a1.y, a1.z, a1.w};
#pragma unroll
  for (int j = 0; j < 8; ++j) {
    unsigned short h = f2bf(xv[j]);
    hi[j] = (short)h;
    lo[j] = (short)f2bf(xv[j] - bf2f(h));
  }
}
// TRUNCATION hi/lo split for the qkv hot loop (R4-proven).
__device__ __forceinline__ void cvt8t(float4 a0, float4 a1, s16x8& hi, s16x8& lo) {
  float xv[8] = {a0.x, a0.y, a0.z, a0.w, a1.x, a1.y, a1.z, a1.w};
  unsigned hu[8], lu[8];
#pragma unroll
  for (int j = 0; j < 8; ++j) {
    union { float f; unsigned u; } c; c.f = xv[j];
    hu[j] = c.u;
    union { unsigned u; float f; } hf; hf.u = c.u & 0xFFFF0000u;
    union { float f; unsigned u; } r; r.f = xv[j] - hf.f;
    lu[j] = r.u;
  }
  union { s16x8 v; unsigned u[4]; } H, L;
#pragma unroll
  for (int j = 0; j < 4; ++j) {
    H.u[j] = (hu[2 * j] >> 16) | (hu[2 * j + 1] & 0xFFFF0000u);
    L.u[j] = (lu[2 * j] >> 16) | (lu[2 * j + 1] & 0xFFFF0000u);
  }
  hi = H.v; lo = L.v;
}

// global -> LDS direct DMA, 16B per lane (wave writes base + lane*16).
__device__ __forceinline__ void gl16(const void* g, void* l) {
  __builtin_amdgcn_global_load_lds(
      (const __attribute__((address_space(1))) void*)g,
      (__attribute__((address_space(3))) void*)l, 16, 0, 0);
}

// ---------------- Kernel 0: W -> W^T hi/lo bf16 (verbatim) ---------------
__global__ __launch_bounds__(256) void wconv(
    const float* __restrict__ Wq, const float* __restrict__ Wk,
    const float* __restrict__ Wv, unsigned short* __restrict__ wt_hi,
    unsigned short* __restrict__ wt_lo) {
  const int n3 = blockIdx.x;
  const int which = n3 >> 6, n = n3 & 63;
  const float* W = (which == 0) ? Wq : (which == 1) ? Wk : Wv;
#pragma unroll
  for (int i = 0; i < 4; ++i) {
    int k = i * 256 + threadIdx.x;
    float x = W[(size_t)k * HS + n];
    unsigned short h = f2bf(x);
    wt_hi[(size_t)n3 * EMB + k] = h;
    wt_lo[(size_t)n3 * EMB + k] = f2bf(x - bf2f(h));
  }
}

// ---------------- Kernel 1: QKV projection v10 (R9, race-fixed T4) -------
// counted vmcnt + raw barrier, order-pinned with sched_barrier(0) (#18).
// NEW in R10: qf is stored PRE-SCALED by log2(e) so attn_part can use a
// bare v_exp_f32 (exp2) instead of __expf's mul+exp.
__global__ __launch_bounds__(512) void qkv_mfma(
    const float* __restrict__ inp, const unsigned short* __restrict__ wt_hi,
    const unsigned short* __restrict__ wt_lo, float* __restrict__ qf,
    unsigned short* __restrict__ khi, unsigned short* __restrict__ klo,
    unsigned short* __restrict__ vtb) {
  __shared__ __align__(16) unsigned short S0[24576];
  __shared__ __align__(16) unsigned short S1[24576];
  const int t = threadIdx.x, lane = t & 63, w = t >> 6;
  const int m = lane & 15, quad = lane >> 4;
  const int mg = w >> 1, ng = w & 1;   // 4 row-groups x 2 col-groups
  const int tok0 = blockIdx.x * 64;
  const int arow = tok0 + mg * 16 + m;

  f32x4 acc[6];
#pragma unroll
  for (int nt = 0; nt < 6; ++nt) acc[nt] = (f32x4){0.f, 0.f, 0.f, 0.f};

  const int rl = lane >> 3;
  const int cl = ((lane & 7) ^ rl) * 8;
  const unsigned short* ghi = wt_hi + (size_t)(w * 8 + rl) * EMB + cl;
  const unsigned short* glo = wt_lo + (size_t)(w * 8 + rl) * EMB + cl;
  unsigned short* const l0 = S0 + w * 512;
  unsigned short* const l1 = S1 + w * 512;

#define SB0() __builtin_amdgcn_sched_barrier(0)

#define STAGE(LB, K0)                                    \
  gl16(ghi + (K0), (LB));                                \
  gl16(ghi + 64 * EMB + (K0), (LB) + 4096);              \
  gl16(ghi + 128 * EMB + (K0), (LB) + 8192);             \
  gl16(glo + (K0), (LB) + 12288);                        \
  gl16(glo + 64 * EMB + (K0), (LB) + 16384);             \
  gl16(glo + 128 * EMB + (K0), (LB) + 20480);            \
  SB0();  /* pin: stages issue before everything after */

#define LOAD_A(K0, PA0, PA1, PA2, PA3)                               \
  {                                                                  \
    const float* ap = &inp[(size_t)arow * EMB + (K0) + quad * 8];    \
    PA0 = *(const float4*)ap;        PA1 = *(const float4*)(ap + 4); \
    PA2 = *(const float4*)(ap + 32); PA3 = *(const float4*)(ap + 36);\
  }

// counted-vmcnt barrier (T4), order-pinned both sides (rule #18).
#define VMBAR(N)                                                        \
  {                                                                     \
    SB0();                                                              \
    asm volatile("s_waitcnt vmcnt(" #N ") lgkmcnt(0)" ::: "memory");    \
    SB0();                                                              \
    __builtin_amdgcn_s_barrier();                                       \
  }

  const int csw0 = (quad ^ (m & 7)) * 8;        // cc = 0 (K-shorts 0..31)
  const int csw1 = ((quad + 4) ^ (m & 7)) * 8;  // cc = 1 (K-shorts 32..63)

#define QKV_TILE(S, AH0, AL0, AH1, AL1)                                      \
  {                                                                          \
    _Pragma("unroll")                                                        \
    for (int nt = 0; nt < 6; ++nt) {                                         \
      const int bb = (ng * 96 + nt * 16 + m) * 64;                           \
      f32x4 a = acc[nt];                                                     \
      {                                                                      \
        s16x8 bh = *(const s16x8*)&S[bb + csw0];                             \
        s16x8 bl = *(const s16x8*)&S[12288 + bb + csw0];                     \
        a = __builtin_amdgcn_mfma_f32_16x16x32_bf16(AH0, bh, a, 0, 0, 0);    \
        a = __builtin_amdgcn_mfma_f32_16x16x32_bf16(AH0, bl, a, 0, 0, 0);    \
        a = __builtin_amdgcn_mfma_f32_16x16x32_bf16(AL0, bh, a, 0, 0, 0);    \
      }                                                                      \
      {                                                                      \
        s16x8 bh = *(const s16x8*)&S[bb + csw1];                             \
        s16x8 bl = *(const s16x8*)&S[12288 + bb + csw1];                     \
        a = __builtin_amdgcn_mfma_f32_16x16x32_bf16(AH1, bh, a, 0, 0, 0);    \
        a = __builtin_amdgcn_mfma_f32_16x16x32_bf16(AH1, bl, a, 0, 0, 0);    \
        a = __builtin_amdgcn_mfma_f32_16x16x32_bf16(AL1, bh, a, 0, 0, 0);    \
      }                                                                      \
      acc[nt] = a;                                                           \
    }                                                                        \
  }

  float4 paA0, paA1, paA2, paA3;
  float4 paB0, paB1, paB2, paB3;

  STAGE(l0, 0);
  LOAD_A(0, paA0, paA1, paA2, paA3);
  LOAD_A(64, paB0, paB1, paB2, paB3);
  VMBAR(8);  // stages drained; 8 A-loads stay in flight

#pragma unroll 1
  for (int kc = 0; kc < 8; ++kc) {
    STAGE(l1, (2 * kc + 1) * 64);
    {
      s16x8 ah0, al0, ah1, al1;
      cvt8t(paA0, paA1, ah0, al0);
      cvt8t(paA2, paA3, ah1, al1);
      if (kc < 7) { LOAD_A((2 * kc + 2) * 64, paA0, paA1, paA2, paA3); }
      QKV_TILE(S0, ah0, al0, ah1, al1);
    }
    if (kc < 7) { VMBAR(4); } else { VMBAR(0); }
    if (kc < 7) { STAGE(l0, (2 * kc + 2) * 64); }
    {
      s16x8 ah0, al0, ah1, al1;
      cvt8t(paB0, paB1, ah0, al0);
      cvt8t(paB2, paB3, ah1, al1);
      if (kc < 7) { LOAD_A((2 * kc + 3) * 64, paB0, paB1, paB2, paB3); }
      QKV_TILE(S1, ah0, al0, ah1, al1);
    }
    if (kc < 7) VMBAR(4);
  }

#undef STAGE
#undef LOAD_A
#undef QKV_TILE
#undef VMBAR
#undef SB0

  // epilogue: C row = quad*4+r (token), col = m
#pragma unroll
  for (int nt = 0; nt < 6; ++nt) {
    int n3 = ng * 96 + nt * 16 + m;
    int which = n3 >> 6, col = n3 & 63;
#pragma unroll
    for (int r = 0; r < 4; ++r) {
      int tok = tok0 + mg * 16 + quad * 4 + r;
      float val = acc[nt][r];
      if (which == 0) {
        // pre-scale by log2(e): attn uses exp2 directly (saves 16 v_mul/iter)
        qf[(size_t)tok * HS + col] = val * 1.44269504088896f;
      } else if (which == 1) {
        unsigned short h = f2bf(val);
        khi[(size_t)tok * HS + col] = h;
        klo[(size_t)tok * HS + col] = f2bf(val - bf2f(h));
      } else {
        vtb[(size_t)(tok >> 6) * 4096 + (size_t)col * 64 + (tok & 63)] = f2bf(val);
      }
    }
  }
}

// ---------------- Kernel 2a: flash partials (R10: VALU-cut softmax) -------
// Changes vs R9 (geometry/sync identical): exp2f on pre-scaled scores
// (q carries log2e), v_cvt_pk_bf16_f32 for P and O packs (8 instrs vs
// ~80 manual-RNE ops), tree-structured l_st sum.
__global__ __launch_bounds__(256) void attn_part(
    const float* __restrict__ q, const unsigned short* __restrict__ khi,
    const unsigned short* __restrict__ klo, const unsigned short* __restrict__ vt,
    unsigned short* __restrict__ partO, float* __restrict__ partML) {
  __shared__ unsigned short Khi_s[64 * 72];
  __shared__ unsigned short Klo_s[64 * 72];
  __shared__ unsigned short Vt_s[64 * 72];
  __shared__ unsigned short P_s[4 * 16 * 72];
  const int t = threadIdx.x;
  const int lane = t & 63, w = t >> 6;
  const int m = lane & 15, quad = lane >> 4;

  int u = blockIdx.x;
  const int b = u / 160;
  u -= b * 160;
  int qtile = 0, c = 0;
  {
    int acc2 = 0;
    for (int qq = 0; qq < 64; ++qq) {
      int ncq = (qq >> 4) + 1;
      if (u < acc2 + ncq) { qtile = qq; c = u - acc2; break; }
      acc2 += ncq;
    }
  }
  const int kt0 = c * 16;
  const int kt1 = (kt0 + 16 < qtile + 1) ? kt0 + 16 : qtile + 1;

  const size_t qrow0 = (size_t)b * T_SEQ + (size_t)qtile * 64;
  const size_t krowbase = (size_t)b * T_SEQ;
  const int q_loc = w * 16 + m;

  s16x8 qh[2], ql[2];
#pragma unroll
  for (int cc = 0; cc < 2; ++cc) {
    const float* qp = &q[(qrow0 + q_loc) * HS + cc * 32 + quad * 8];
    cvt8(*(const float4*)qp, *(const float4*)(qp + 4), qh[cc], ql[cc]);
  }

  float l_st = 0.f;
  f32x4 o[4];
#pragma unroll
  for (int hb = 0; hb < 4; ++hb) o[hb] = (f32x4){0.f, 0.f, 0.f, 0.f};

  const int r0 = t >> 3, ch0 = t & 7;
  const int r1 = (256 + t) >> 3, ch1 = t & 7;

  uint4 pk0h, pk0l, pv0, pk1h, pk1l, pv1;
  {
    size_t g0 = (krowbase + (size_t)kt0 * 64 + r0) * HS + ch0 * 8;
    size_t g1 = (krowbase + (size_t)kt0 * 64 + r1) * HS + ch1 * 8;
    pk0h = *(const uint4*)&khi[g0]; pk0l = *(const uint4*)&klo[g0];
    pk1h = *(const uint4*)&khi[g1]; pk1l = *(const uint4*)&klo[g1];
    size_t v0 = (size_t)(b * 64 + kt0) * 4096 + (size_t)r0 * 64 + ch0 * 8;
    size_t v1 = (size_t)(b * 64 + kt0) * 4096 + (size_t)r1 * 64 + ch1 * 8;
    pv0 = *(const uint4*)&vt[v0]; pv1 = *(const uint4*)&vt[v1];
  }

  for (int kt = kt0; kt < kt1; ++kt) {
    __syncthreads();
    *(uint4*)&Khi_s[r0 * 72 + ch0 * 8] = pk0h;
    *(uint4*)&Klo_s[r0 * 72 + ch0 * 8] = pk0l;
    *(uint4*)&Vt_s[r0 * 72 + ch0 * 8] = pv0;
    *(uint4*)&Khi_s[r1 * 72 + ch1 * 8] = pk1h;
    *(uint4*)&Klo_s[r1 * 72 + ch1 * 8] = pk1l;
    *(uint4*)&Vt_s[r1 * 72 + ch1 * 8] = pv1;
    __syncthreads();

    if (kt + 1 < kt1) {
      size_t g0 = (krowbase + (size_t)(kt + 1) * 64 + r0) * HS + ch0 * 8;
      size_t g1 = (krowbase + (size_t)(kt + 1) * 64 + r1) * HS + ch1 * 8;
      pk0h = *(const uint4*)&khi[g0]; pk0l = *(const uint4*)&klo[g0];
      pk1h = *(const uint4*)&khi[g1]; pk1l = *(const uint4*)&klo[g1];
      size_t v0 = (size_t)(b * 64 + kt + 1) * 4096 + (size_t)r0 * 64 + ch0 * 8;
      size_t v1 = (size_t)(b * 64 + kt + 1) * 4096 + (size_t)r1 * 64 + ch1 * 8;
      pv0 = *(const uint4*)&vt[v0]; pv1 = *(const uint4*)&vt[v1];
    }

    f32x4 st[4];
#pragma unroll
    for (int cb = 0; cb < 4; ++cb) {
      st[cb] = (f32x4){0.f, 0.f, 0.f, 0.f};
#pragma unroll
      for (int cc = 0; cc < 2; ++cc) {
        s16x8 bh = *(const s16x8*)&Khi_s[(cb * 16 + m) * 72 + cc * 32 + quad * 8];
        s16x8 bl = *(const s16x8*)&Klo_s[(cb * 16 + m) * 72 + cc * 32 + quad * 8];
        st[cb] = __builtin_amdgcn_mfma_f32_16x16x32_bf16(bh, qh[cc], st[cb], 0, 0, 0);
        st[cb] = __builtin_amdgcn_mfma_f32_16x16x32_bf16(bl, qh[cc], st[cb], 0, 0, 0);
        st[cb] = __builtin_amdgcn_mfma_f32_16x16x32_bf16(bh, ql[cc], st[cb], 0, 0, 0);
      }
    }
    if (kt == qtile) {
#pragma unroll
      for (int cb = 0; cb < 4; ++cb)
#pragma unroll
        for (int r = 0; r < 4; ++r)
          if (cb * 16 + quad * 4 + r > q_loc) st[cb][r] = -1e30f;
    }
    // scores are pre-scaled by log2(e) -> bare exp2. Tree-sum the 16 adds.
    float tc[4];
#pragma unroll
    for (int cb = 0; cb < 4; ++cb) {
#pragma unroll
      for (int r = 0; r < 4; ++r) st[cb][r] = exp2f(st[cb][r]);
      tc[cb] = (st[cb][0] + st[cb][1]) + (st[cb][2] + st[cb][3]);
    }
    l_st += (tc[0] + tc[1]) + (tc[2] + tc[3]);
#pragma unroll
    for (int cb = 0; cb < 4; ++cb) {
      uint2 pk;
      pk.x = cvtpk(st[cb][0], st[cb][1]);
      pk.y = cvtpk(st[cb][2], st[cb][3]);
      *(uint2*)&P_s[q_loc * 72 + cb * 16 + quad * 4] = pk;
    }
    s16x8 pf[2];
#pragma unroll
    for (int cc = 0; cc < 2; ++cc)
      pf[cc] = *(const s16x8*)&P_s[q_loc * 72 + cc * 32 + quad * 8];
#pragma unroll
    for (int hb = 0; hb < 4; ++hb) {
#pragma unroll
      for (int cc = 0; cc < 2; ++cc) {
        s16x8 vf = *(const s16x8*)&Vt_s[(hb * 16 + m) * 72 + cc * 32 + quad * 8];
        o[hb] = __builtin_amdgcn_mfma_f32_16x16x32_bf16(vf, pf[cc], o[hb], 0, 0, 0);
      }
    }
  }

  l_st += __shfl_xor(l_st, 16, 64);
  l_st += __shfl_xor(l_st, 32, 64);

  const int slot = ((b * 64 + qtile) << 2) + c;
  unsigned short* Op = partO + (size_t)slot * 4096;
#pragma unroll
  for (int hb = 0; hb < 4; ++hb) {
    uint2 pk;
    pk.x = cvtpk(o[hb][0], o[hb][1]);
    pk.y = cvtpk(o[hb][2], o[hb][3]);
    *(uint2*)&Op[q_loc * 64 + hb * 16 + quad * 4] = pk;
  }
  if (quad == 0) partML[(size_t)slot * 64 + q_loc] = l_st;
}

// ---------------- Kernel 2b: combine = plain sums (flat softmax) ----------
__global__ __launch_bounds__(256) void attn_combine(
    const unsigned short* __restrict__ partO, const float* __restrict__ partML,
    float* __restrict__ out) {
  const int qtile = blockIdx.x, b = blockIdx.y;
  const int t = threadIdx.x;
  const int row = t >> 2, hg = t & 3;
  const int nc = (qtile >> 4) + 1;
  const int slot0 = (b * 64 + qtile) << 2;

  float lsum = 0.f;
  for (int i = 0; i < nc; ++i) lsum += partML[(size_t)(slot0 + i) * 64 + row];
  const float inv = 1.f / (lsum * 8.0f);  // ref divides by sqrt(64) after softmax

  float acc[16];
#pragma unroll
  for (int e = 0; e < 16; ++e) acc[e] = 0.f;
  for (int i = 0; i < nc; ++i) {
    const unsigned short* Op =
        partO + (size_t)(slot0 + i) * 4096 + row * 64 + hg * 16;
    uint4 u0 = *(const uint4*)Op;
    uint4 u1 = *(const uint4*)(Op + 8);
    unsigned uv[8] = {u0.x, u0.y, u0.z, u0.w, u1.x, u1.y, u1.z, u1.w};
#pragma unroll
    for (int e = 0; e < 8; ++e) {
      acc[2 * e] += bf2f((unsigned short)(uv[e] & 0xFFFF));
      acc[2 * e + 1] += bf2f((unsigned short)(uv[e] >> 16));
    }
  }
  float* op = &out[((size_t)b * T_SEQ + (size_t)qtile * 64 + row) * HS + hg * 16];
#pragma unroll
  for (int v = 0; v < 4; ++v) {
    float4 r;
    r.x = acc[4 * v + 0] * inv; r.y = acc[4 * v + 1] * inv;
    r.z = acc[4 * v + 2] * inv; r.w = acc[4 * v + 3] * inv;
    ((float4*)op)[v] = r;
  }
}

extern "C" void kernel_launch(void* const* d_in, const int* in_sizes, int n_in,
                              void* d_out, int out_size, void* d_ws, size_t ws_size,
                              hipStream_t stream) {
  const float* inp = (const float*)d_in[0];
  const float* Wq  = (const float*)d_in[1];
  const float* Wk  = (const float*)d_in[2];
  const float* Wv  = (const float*)d_in[3];
  float* out = (float*)d_out;

  // ws: qf 4MB | khi 2MB | klo 2MB | vt 2MB | wt_hi .375MB | wt_lo .375MB
  //     | partO bf16 8MB | partML 256KB  (~19 MB)
  char* base = (char*)d_ws;
  float* qf = (float*)base;
  unsigned short* khi = (unsigned short*)(base + (size_t)BT * HS * 4);
  unsigned short* klo = khi + (size_t)BT * HS;
  unsigned short* vtb = klo + (size_t)BT * HS;
  unsigned short* wt_hi = vtb + (size_t)BT * HS;
  unsigned short* wt_lo = wt_hi + (size_t)192 * EMB;
  unsigned short* partO = wt_lo + (size_t)192 * EMB;
  float* partML = (float*)(partO + (size_t)1024 * 4096);

  wconv<<<dim3(192), dim3(256), 0, stream>>>(Wq, Wk, Wv, wt_hi, wt_lo);
  qkv_mfma<<<dim3(BT / 64), dim3(512), 0, stream>>>(inp, wt_hi, wt_lo, qf, khi, klo, vtb);
  attn_part<<<dim3(640), dim3(256), 0, stream>>>(qf, khi, klo, vtb, partO, partML);
  attn_combine<<<dim3(64, NBATCH), dim3(256), 0, stream>>>(partO, partML, out);
}